// Round 2
// baseline (2345.916 us; speedup 1.0000x reference)
//
#include <hip/hip_runtime.h>

#define N_NODES 50000
#define F_IN 256
#define F_H 128
#define F_OUT 64
#define E_MAX 1600000
#define NEG_SLOPE 0.2f
#define EPS_F 1e-16f

// ---------------- device-global scratch ------------------------------------
__device__ float g_Wl1t[F_H * F_IN];    // transposed [n][k]
__device__ float g_Wr1t[F_H * F_IN];
__device__ float g_Wl2t[F_OUT * F_H];
__device__ float g_Wr2t[F_OUT * F_H];
__device__ float g_xl1[(size_t)N_NODES * F_H];
__device__ float g_xr1[(size_t)N_NODES * F_H];
__device__ float g_h[(size_t)N_NODES * F_H];      // agg1, then relu'd in place
__device__ float g_xl2[(size_t)N_NODES * F_OUT];
__device__ float g_xr2[(size_t)N_NODES * F_OUT];
__device__ float g_agg2[(size_t)N_NODES * F_OUT];
__device__ float g_e[E_MAX];                      // logits, then exp(e-m) in place
__device__ unsigned g_mu[N_NODES];                // monotone-encoded float max
__device__ float g_s[N_NODES];

// ---------------- helpers ---------------------------------------------------
// clamp external loads: no-op for valid N(0,1)-scale data, kills NaN/Inf/garbage
__device__ inline float san(float v) { return fminf(fmaxf(v, -64.f), 64.f); }

// monotone order-preserving float<->uint encoding (for atomicMax on floats)
__device__ inline unsigned enc_f(float v) {
    unsigned b = __float_as_uint(v);
    return (b & 0x80000000u) ? ~b : (b | 0x80000000u);
}
__device__ inline float dec_f(unsigned u) {
    return (u & 0x80000000u) ? __uint_as_float(u ^ 0x80000000u)
                             : __uint_as_float(~u);
}

// ---------------- weight transpose (f32 -> f32 [n][k], sanitized) -----------
__global__ void wconv_all(const float* __restrict__ Wl1,
                          const float* __restrict__ Wr1,
                          const float* __restrict__ Wl2,
                          const float* __restrict__ Wr2) {
    int i = blockIdx.x * blockDim.x + threadIdx.x;
    if (i < F_IN * F_H) {
        int k = i / F_H, n = i % F_H;
        g_Wl1t[n * F_IN + k] = san(Wl1[i]);
        g_Wr1t[n * F_IN + k] = san(Wr1[i]);
    }
    if (i < F_H * F_OUT) {
        int k = i / F_OUT, n = i % F_OUT;
        g_Wl2t[n * F_H + k] = san(Wl2[i]);
        g_Wr2t[n * F_H + k] = san(Wr2[i]);
    }
}

// ---------------- GEMM 1: xl1/xr1 = x @ Wl1 / x @ Wr1  (M=50000,K=256,N=128)
__global__ __launch_bounds__(256) void gemm1(const float* __restrict__ x) {
    __shared__ float As[32 * F_IN];              // 32 KiB
    int m0 = blockIdx.x * 32;
    int tid = threadIdx.x;
    for (int i = tid; i < 32 * (F_IN / 4); i += 256) {   // 2048 float4
        int r = i >> 6;                          // /(F_IN/4)
        int k4 = i & 63;
        int m = m0 + r;
        float4 a = make_float4(0.f, 0.f, 0.f, 0.f);
        if (m < N_NODES) a = ((const float4*)(x + (size_t)m * F_IN))[k4];
        a.x = san(a.x); a.y = san(a.y); a.z = san(a.z); a.w = san(a.w);
        ((float4*)As)[i] = a;
    }
    __syncthreads();
    int c = tid & 127;
    int hh = tid >> 7;                           // 0/1 row-half
    const float* __restrict__ bl = g_Wl1t + c * F_IN;
    const float* __restrict__ br = g_Wr1t + c * F_IN;
    float accl[16], accr[16];
#pragma unroll
    for (int r = 0; r < 16; ++r) { accl[r] = 0.f; accr[r] = 0.f; }
    for (int k = 0; k < F_IN; k += 4) {
        float4 vl = *(const float4*)(bl + k);
        float4 vr = *(const float4*)(br + k);
#pragma unroll
        for (int r = 0; r < 16; ++r) {
            float4 a = *(const float4*)(&As[(hh * 16 + r) * F_IN + k]);
            accl[r] = fmaf(a.x, vl.x, accl[r]);
            accl[r] = fmaf(a.y, vl.y, accl[r]);
            accl[r] = fmaf(a.z, vl.z, accl[r]);
            accl[r] = fmaf(a.w, vl.w, accl[r]);
            accr[r] = fmaf(a.x, vr.x, accr[r]);
            accr[r] = fmaf(a.y, vr.y, accr[r]);
            accr[r] = fmaf(a.z, vr.z, accr[r]);
            accr[r] = fmaf(a.w, vr.w, accr[r]);
        }
    }
#pragma unroll
    for (int r = 0; r < 16; ++r) {
        int m = m0 + hh * 16 + r;
        if (m < N_NODES) {
            g_xl1[(size_t)m * F_H + c] = accl[r];
            g_xr1[(size_t)m * F_H + c] = accr[r];
        }
    }
}

// ---------------- GEMM 2: xl2/xr2 = h @ Wl2 / h @ Wr2  (M=50000,K=128,N=64)
__global__ __launch_bounds__(128) void gemm2() {
    __shared__ float As[32 * F_H];               // 16 KiB
    int m0 = blockIdx.x * 32;
    int tid = threadIdx.x;
    for (int i = tid; i < 32 * (F_H / 4); i += 128) {    // 1024 float4
        int r = i >> 5;
        int k4 = i & 31;
        int m = m0 + r;
        float4 a = make_float4(0.f, 0.f, 0.f, 0.f);
        if (m < N_NODES) a = ((const float4*)(g_h + (size_t)m * F_H))[k4];
        ((float4*)As)[i] = a;
    }
    __syncthreads();
    int c = tid & 63;
    int hh = tid >> 6;
    const float* __restrict__ bl = g_Wl2t + c * F_H;
    const float* __restrict__ br = g_Wr2t + c * F_H;
    float accl[16], accr[16];
#pragma unroll
    for (int r = 0; r < 16; ++r) { accl[r] = 0.f; accr[r] = 0.f; }
    for (int k = 0; k < F_H; k += 4) {
        float4 vl = *(const float4*)(bl + k);
        float4 vr = *(const float4*)(br + k);
#pragma unroll
        for (int r = 0; r < 16; ++r) {
            float4 a = *(const float4*)(&As[(hh * 16 + r) * F_H + k]);
            accl[r] = fmaf(a.x, vl.x, accl[r]);
            accl[r] = fmaf(a.y, vl.y, accl[r]);
            accl[r] = fmaf(a.z, vl.z, accl[r]);
            accl[r] = fmaf(a.w, vl.w, accl[r]);
            accr[r] = fmaf(a.x, vr.x, accr[r]);
            accr[r] = fmaf(a.y, vr.y, accr[r]);
            accr[r] = fmaf(a.z, vr.z, accr[r]);
            accr[r] = fmaf(a.w, vr.w, accr[r]);
        }
    }
#pragma unroll
    for (int r = 0; r < 16; ++r) {
        int m = m0 + hh * 16 + r;
        if (m < N_NODES) {
            g_xl2[(size_t)m * F_OUT + c] = accl[r];
            g_xr2[(size_t)m * F_OUT + c] = accr[r];
        }
    }
}

// ---------------- init kernels ----------------------------------------------
__global__ void init_l1() {
    int i = blockIdx.x * blockDim.x + threadIdx.x;
    if (i < N_NODES * F_H) g_h[i] = 0.f;
    if (i < N_NODES) { g_mu[i] = 0u; g_s[i] = 0.f; }
}
__global__ void init_l2() {
    int i = blockIdx.x * blockDim.x + threadIdx.x;
    if (i < N_NODES * F_OUT) g_agg2[i] = 0.f;
    if (i < N_NODES) { g_mu[i] = 0u; g_s[i] = 0.f; }
}

// ---------------- edge phase: logits + segment max --------------------------
__global__ __launch_bounds__(256) void edge_logits1(const int* __restrict__ src,
                                                    const int* __restrict__ dst,
                                                    const float* __restrict__ att,
                                                    int E) {
    int k = (blockIdx.x * 256 + threadIdx.x) >> 6;
    if (k >= E) return;
    int lane = threadIdx.x & 63;
    int s = src[k], d = dst[k];
    size_t so = (size_t)s * F_H, dof = (size_t)d * F_H;
    float v = 0.f;
#pragma unroll
    for (int f0 = 0; f0 < F_H; f0 += 64) {
        int f = f0 + lane;
        float z = g_xl1[so + f] + g_xr1[dof + f];
        z = (z >= 0.f) ? z : NEG_SLOPE * z;
        v += z * san(att[f]);
    }
#pragma unroll
    for (int off = 32; off > 0; off >>= 1) v += __shfl_xor(v, off, 64);
    if (lane == 0) { g_e[k] = v; atomicMax(&g_mu[d], enc_f(v)); }
}

__global__ __launch_bounds__(256) void edge_logits2(const int* __restrict__ src,
                                                    const int* __restrict__ dst,
                                                    const float* __restrict__ att,
                                                    int E) {
    int k = (blockIdx.x * 256 + threadIdx.x) >> 6;
    if (k >= E) return;
    int lane = threadIdx.x & 63;
    int s = src[k], d = dst[k];
    float z = g_xl2[(size_t)s * F_OUT + lane] + g_xr2[(size_t)d * F_OUT + lane];
    z = (z >= 0.f) ? z : NEG_SLOPE * z;
    float v = z * san(att[lane]);
#pragma unroll
    for (int off = 32; off > 0; off >>= 1) v += __shfl_xor(v, off, 64);
    if (lane == 0) { g_e[k] = v; atomicMax(&g_mu[d], enc_f(v)); }
}

// ---------------- edge phase: exp + segment sum ------------------------------
__global__ void edge_exp(const int* __restrict__ dst, int E) {
    int k = blockIdx.x * blockDim.x + threadIdx.x;
    if (k >= E) return;
    int d = dst[k];
    float m = dec_f(g_mu[d]);
    float t = g_e[k] - m;
    if (!(t <= 0.f)) t = 0.f;       // guards NaN and any m-underestimate
    float a = __expf(t);
    g_e[k] = a;
    atomicAdd(&g_s[d], a);
}

// ---------------- edge phase: weighted scatter-aggregate --------------------
__global__ __launch_bounds__(256) void aggregate1(const int* __restrict__ src,
                                                  const int* __restrict__ dst,
                                                  int E) {
    int k = (blockIdx.x * 256 + threadIdx.x) >> 6;
    if (k >= E) return;
    int lane = threadIdx.x & 63;
    int s = src[k], d = dst[k];
    float alpha = g_e[k] / (g_s[d] + EPS_F);
    alpha = fminf(fmaxf(alpha, 0.f), 1.f);      // no-op when valid
    size_t so = (size_t)s * F_H, dof = (size_t)d * F_H;
#pragma unroll
    for (int f0 = 0; f0 < F_H; f0 += 64) {
        int f = f0 + lane;
        atomicAdd(&g_h[dof + f], alpha * g_xl1[so + f]);
    }
}

__global__ __launch_bounds__(256) void aggregate2(const int* __restrict__ src,
                                                  const int* __restrict__ dst,
                                                  int E) {
    int k = (blockIdx.x * 256 + threadIdx.x) >> 6;
    if (k >= E) return;
    int lane = threadIdx.x & 63;
    int s = src[k], d = dst[k];
    float alpha = g_e[k] / (g_s[d] + EPS_F);
    alpha = fminf(fmaxf(alpha, 0.f), 1.f);
    atomicAdd(&g_agg2[(size_t)d * F_OUT + lane], alpha * g_xl2[(size_t)s * F_OUT + lane]);
}

// ---------------- epilogues --------------------------------------------------
__global__ void bias_relu1(const float* __restrict__ b) {
    int i = blockIdx.x * blockDim.x + threadIdx.x;
    if (i >= N_NODES * F_H) return;
    float v = g_h[i] + san(b[i & (F_H - 1)]);
    g_h[i] = v > 0.f ? v : 0.f;
}

__global__ void bias_out2(const float* __restrict__ b,
                          float* __restrict__ out) {
    int i = blockIdx.x * blockDim.x + threadIdx.x;
    if (i >= N_NODES * F_OUT) return;
    out[i] = g_agg2[i] + san(b[i & (F_OUT - 1)]);
}

// ---------------- launch ------------------------------------------------------
extern "C" void kernel_launch(void* const* d_in, const int* in_sizes, int n_in,
                              void* d_out, int out_size, void* d_ws, size_t ws_size,
                              hipStream_t stream) {
    const float* x    = (const float*)d_in[0];
    const int*   ei   = (const int*)d_in[1];
    const float* Wl1  = (const float*)d_in[2];
    const float* Wr1  = (const float*)d_in[3];
    const float* att1 = (const float*)d_in[4];
    const float* b1   = (const float*)d_in[5];
    const float* Wl2  = (const float*)d_in[6];
    const float* Wr2  = (const float*)d_in[7];
    const float* att2 = (const float*)d_in[8];
    const float* b2   = (const float*)d_in[9];

    int E = in_sizes[1] / 2;
    const int* src = ei;
    const int* dst = ei + E;

    int gM  = (N_NODES + 31) / 32;
    int gE4 = (E + 3) / 4;               // one wave (64 lanes) per edge
    int gE  = (E + 255) / 256;

    wconv_all<<<(F_IN * F_H + 255) / 256, 256, 0, stream>>>(Wl1, Wr1, Wl2, Wr2);

    // ---- layer 1 ----
    gemm1<<<gM, 256, 0, stream>>>(x);
    init_l1<<<(N_NODES * F_H + 255) / 256, 256, 0, stream>>>();
    edge_logits1<<<gE4, 256, 0, stream>>>(src, dst, att1, E);
    edge_exp<<<gE, 256, 0, stream>>>(dst, E);
    aggregate1<<<gE4, 256, 0, stream>>>(src, dst, E);
    bias_relu1<<<(N_NODES * F_H + 255) / 256, 256, 0, stream>>>(b1);

    // ---- layer 2 ----
    gemm2<<<gM, 128, 0, stream>>>();
    init_l2<<<(N_NODES * F_OUT + 255) / 256, 256, 0, stream>>>();
    edge_logits2<<<gE4, 256, 0, stream>>>(src, dst, att2, E);
    edge_exp<<<gE, 256, 0, stream>>>(dst, E);
    aggregate2<<<gE4, 256, 0, stream>>>(src, dst, E);
    bias_out2<<<(N_NODES * F_OUT + 255) / 256, 256, 0, stream>>>(b2, (float*)d_out);
}

// Round 3
// 914.106 us; speedup vs baseline: 2.5663x; 2.5663x over previous
//
#include <hip/hip_runtime.h>

#define N_NODES 50000
#define F_IN 256
#define F_H 128
#define F_OUT 64
#define E_MAX 1600000
#define NEG_SLOPE 0.2f
#define EPS_F 1e-16f

// ---------------- device-global scratch ------------------------------------
__device__ float g_Wl1t[F_H * F_IN];    // transposed [n][k]
__device__ float g_Wr1t[F_H * F_IN];
__device__ float g_Wl2t[F_OUT * F_H];
__device__ float g_Wr2t[F_OUT * F_H];
__device__ float g_xl1[(size_t)N_NODES * F_H];
__device__ float g_xr1[(size_t)N_NODES * F_H];
__device__ float g_h[(size_t)N_NODES * F_H];      // layer-1 out (relu'd)
__device__ float g_xl2[(size_t)N_NODES * F_OUT];
__device__ float g_xr2[(size_t)N_NODES * F_OUT];
// CSR by dst
__device__ unsigned g_cnt[N_NODES];
__device__ unsigned g_rowstart[N_NODES + 1];
__device__ unsigned g_cursor[N_NODES];
__device__ int g_src_sorted[E_MAX];

// ---------------- helpers ---------------------------------------------------
__device__ inline float san(float v) { return fminf(fmaxf(v, -64.f), 64.f); }

// ---------------- weight transpose (sanitized) ------------------------------
__global__ void wconv_all(const float* __restrict__ Wl1,
                          const float* __restrict__ Wr1,
                          const float* __restrict__ Wl2,
                          const float* __restrict__ Wr2) {
    int i = blockIdx.x * blockDim.x + threadIdx.x;
    if (i < F_IN * F_H) {
        int k = i / F_H, n = i % F_H;
        g_Wl1t[n * F_IN + k] = san(Wl1[i]);
        g_Wr1t[n * F_IN + k] = san(Wr1[i]);
    }
    if (i < F_H * F_OUT) {
        int k = i / F_OUT, n = i % F_OUT;
        g_Wl2t[n * F_H + k] = san(Wl2[i]);
        g_Wr2t[n * F_H + k] = san(Wr2[i]);
    }
}

// ---------------- CSR build --------------------------------------------------
__global__ void csr_zero() {
    int i = blockIdx.x * blockDim.x + threadIdx.x;
    if (i < N_NODES) g_cnt[i] = 0u;
}
__global__ void csr_hist(const int* __restrict__ dst, int E) {
    int e = blockIdx.x * blockDim.x + threadIdx.x;
    if (e < E) atomicAdd(&g_cnt[dst[e]], 1u);
}
// single-block exclusive scan over 50000 counters (1024 thr x 49 elems)
__global__ __launch_bounds__(1024) void csr_scan(int E) {
    __shared__ unsigned lds[1024];
    const int CH = (N_NODES + 1023) / 1024;       // 49
    int t = threadIdx.x;
    int lo = t * CH, hi = min(lo + CH, N_NODES);
    unsigned part = 0;
    for (int i = lo; i < hi; ++i) part += g_cnt[i];
    lds[t] = part;
    __syncthreads();
    for (int off = 1; off < 1024; off <<= 1) {
        unsigned v = (t >= off) ? lds[t - off] : 0u;
        __syncthreads();
        lds[t] += v;
        __syncthreads();
    }
    unsigned base = (t == 0) ? 0u : lds[t - 1];
    for (int i = lo; i < hi; ++i) {
        g_rowstart[i] = base;
        g_cursor[i] = base;
        base += g_cnt[i];
    }
    if (t == 1023) g_rowstart[N_NODES] = (unsigned)E;
}
__global__ void csr_scatter(const int* __restrict__ src,
                            const int* __restrict__ dst, int E) {
    int e = blockIdx.x * blockDim.x + threadIdx.x;
    if (e >= E) return;
    unsigned pos = atomicAdd(&g_cursor[dst[e]], 1u);
    g_src_sorted[pos] = src[e];
}

// ---------------- GEMM 1: xl1/xr1 = x @ Wl1 / x @ Wr1  (M=50000,K=256,N=128)
__global__ __launch_bounds__(256) void gemm1(const float* __restrict__ x) {
    __shared__ float As[32 * F_IN];              // 32 KiB
    int m0 = blockIdx.x * 32;
    int tid = threadIdx.x;
    for (int i = tid; i < 32 * (F_IN / 4); i += 256) {
        int r = i >> 6;
        int k4 = i & 63;
        int m = m0 + r;
        float4 a = make_float4(0.f, 0.f, 0.f, 0.f);
        if (m < N_NODES) a = ((const float4*)(x + (size_t)m * F_IN))[k4];
        a.x = san(a.x); a.y = san(a.y); a.z = san(a.z); a.w = san(a.w);
        ((float4*)As)[i] = a;
    }
    __syncthreads();
    int c = tid & 127;
    int hh = tid >> 7;
    const float* __restrict__ bl = g_Wl1t + c * F_IN;
    const float* __restrict__ br = g_Wr1t + c * F_IN;
    float accl[16], accr[16];
#pragma unroll
    for (int r = 0; r < 16; ++r) { accl[r] = 0.f; accr[r] = 0.f; }
    for (int k = 0; k < F_IN; k += 4) {
        float4 vl = *(const float4*)(bl + k);
        float4 vr = *(const float4*)(br + k);
#pragma unroll
        for (int r = 0; r < 16; ++r) {
            float4 a = *(const float4*)(&As[(hh * 16 + r) * F_IN + k]);
            accl[r] = fmaf(a.x, vl.x, accl[r]);
            accl[r] = fmaf(a.y, vl.y, accl[r]);
            accl[r] = fmaf(a.z, vl.z, accl[r]);
            accl[r] = fmaf(a.w, vl.w, accl[r]);
            accr[r] = fmaf(a.x, vr.x, accr[r]);
            accr[r] = fmaf(a.y, vr.y, accr[r]);
            accr[r] = fmaf(a.z, vr.z, accr[r]);
            accr[r] = fmaf(a.w, vr.w, accr[r]);
        }
    }
#pragma unroll
    for (int r = 0; r < 16; ++r) {
        int m = m0 + hh * 16 + r;
        if (m < N_NODES) {
            g_xl1[(size_t)m * F_H + c] = accl[r];
            g_xr1[(size_t)m * F_H + c] = accr[r];
        }
    }
}

// ---------------- GEMM 2: xl2/xr2 = h @ Wl2 / h @ Wr2  (M=50000,K=128,N=64)
__global__ __launch_bounds__(128) void gemm2() {
    __shared__ float As[32 * F_H];
    int m0 = blockIdx.x * 32;
    int tid = threadIdx.x;
    for (int i = tid; i < 32 * (F_H / 4); i += 128) {
        int r = i >> 5;
        int k4 = i & 31;
        int m = m0 + r;
        float4 a = make_float4(0.f, 0.f, 0.f, 0.f);
        if (m < N_NODES) a = ((const float4*)(g_h + (size_t)m * F_H))[k4];
        ((float4*)As)[i] = a;
    }
    __syncthreads();
    int c = tid & 63;
    int hh = tid >> 6;
    const float* __restrict__ bl = g_Wl2t + c * F_H;
    const float* __restrict__ br = g_Wr2t + c * F_H;
    float accl[16], accr[16];
#pragma unroll
    for (int r = 0; r < 16; ++r) { accl[r] = 0.f; accr[r] = 0.f; }
    for (int k = 0; k < F_H; k += 4) {
        float4 vl = *(const float4*)(bl + k);
        float4 vr = *(const float4*)(br + k);
#pragma unroll
        for (int r = 0; r < 16; ++r) {
            float4 a = *(const float4*)(&As[(hh * 16 + r) * F_H + k]);
            accl[r] = fmaf(a.x, vl.x, accl[r]);
            accl[r] = fmaf(a.y, vl.y, accl[r]);
            accl[r] = fmaf(a.z, vl.z, accl[r]);
            accl[r] = fmaf(a.w, vl.w, accl[r]);
            accr[r] = fmaf(a.x, vr.x, accr[r]);
            accr[r] = fmaf(a.y, vr.y, accr[r]);
            accr[r] = fmaf(a.z, vr.z, accr[r]);
            accr[r] = fmaf(a.w, vr.w, accr[r]);
        }
    }
#pragma unroll
    for (int r = 0; r < 16; ++r) {
        int m = m0 + hh * 16 + r;
        if (m < N_NODES) {
            g_xl2[(size_t)m * F_OUT + c] = accl[r];
            g_xr2[(size_t)m * F_OUT + c] = accr[r];
        }
    }
}

// ---------------- fused edge phase, layer 1 (F=128, one wave per dst) -------
// flash-style online softmax: gather xl[src] once, use for logit AND accum.
__global__ __launch_bounds__(256) void fuse1(const float* __restrict__ att,
                                             const float* __restrict__ bias) {
    int w = (blockIdx.x * 256 + threadIdx.x) >> 6;   // dst node
    if (w >= N_NODES) return;
    int lane = threadIdx.x & 63;
    int f2 = lane * 2;
    float2 xr   = *(const float2*)(g_xr1 + (size_t)w * F_H + f2);
    float2 attv = make_float2(san(att[f2]), san(att[f2 + 1]));
    int beg = (int)g_rowstart[w], end = (int)g_rowstart[w + 1];
    float m = -INFINITY, ssum = 0.f;
    float2 acc = make_float2(0.f, 0.f);
    for (int b0 = beg; b0 < end; b0 += 64) {
        int myidx = b0 + lane;
        int mysrc = (myidx < end) ? g_src_sorted[myidx] : 0;
        int n = min(64, end - b0);
        for (int j = 0; j < n; ++j) {
            int s = __shfl(mysrc, j, 64);
            float2 xl = *(const float2*)(g_xl1 + (size_t)s * F_H + f2);
            float z0 = xl.x + xr.x, z1 = xl.y + xr.y;
            z0 = (z0 >= 0.f) ? z0 : NEG_SLOPE * z0;
            z1 = (z1 >= 0.f) ? z1 : NEG_SLOPE * z1;
            float part = z0 * attv.x + z1 * attv.y;
#pragma unroll
            for (int off = 32; off > 0; off >>= 1) part += __shfl_xor(part, off, 64);
            float mn = fmaxf(m, part);
            float sc = __expf(m - mn);       // 0 on first edge (m=-inf)
            float p  = __expf(part - mn);
            ssum = ssum * sc + p;
            m = mn;
            acc.x = acc.x * sc + p * xl.x;
            acc.y = acc.y * sc + p * xl.y;
        }
    }
    float inv = 1.f / (ssum + EPS_F);
    float o0 = acc.x * inv + san(bias[f2]);
    float o1 = acc.y * inv + san(bias[f2 + 1]);
    o0 = o0 > 0.f ? o0 : 0.f;                // relu between layers
    o1 = o1 > 0.f ? o1 : 0.f;
    *(float2*)(g_h + (size_t)w * F_H + f2) = make_float2(o0, o1);
}

// ---------------- fused edge phase, layer 2 (F=64, one wave per dst) --------
__global__ __launch_bounds__(256) void fuse2(const float* __restrict__ att,
                                             const float* __restrict__ bias,
                                             float* __restrict__ out) {
    int w = (blockIdx.x * 256 + threadIdx.x) >> 6;
    if (w >= N_NODES) return;
    int lane = threadIdx.x & 63;
    float xr   = g_xr2[(size_t)w * F_OUT + lane];
    float attv = san(att[lane]);
    int beg = (int)g_rowstart[w], end = (int)g_rowstart[w + 1];
    float m = -INFINITY, ssum = 0.f, acc = 0.f;
    for (int b0 = beg; b0 < end; b0 += 64) {
        int myidx = b0 + lane;
        int mysrc = (myidx < end) ? g_src_sorted[myidx] : 0;
        int n = min(64, end - b0);
        for (int j = 0; j < n; ++j) {
            int s = __shfl(mysrc, j, 64);
            float xl = g_xl2[(size_t)s * F_OUT + lane];
            float z = xl + xr;
            z = (z >= 0.f) ? z : NEG_SLOPE * z;
            float part = z * attv;
#pragma unroll
            for (int off = 32; off > 0; off >>= 1) part += __shfl_xor(part, off, 64);
            float mn = fmaxf(m, part);
            float sc = __expf(m - mn);
            float p  = __expf(part - mn);
            ssum = ssum * sc + p;
            m = mn;
            acc = acc * sc + p * xl;
        }
    }
    out[(size_t)w * F_OUT + lane] = acc / (ssum + EPS_F) + san(bias[lane]);
}

// ---------------- launch ------------------------------------------------------
extern "C" void kernel_launch(void* const* d_in, const int* in_sizes, int n_in,
                              void* d_out, int out_size, void* d_ws, size_t ws_size,
                              hipStream_t stream) {
    const float* x    = (const float*)d_in[0];
    const int*   ei   = (const int*)d_in[1];
    const float* Wl1  = (const float*)d_in[2];
    const float* Wr1  = (const float*)d_in[3];
    const float* att1 = (const float*)d_in[4];
    const float* b1   = (const float*)d_in[5];
    const float* Wl2  = (const float*)d_in[6];
    const float* Wr2  = (const float*)d_in[7];
    const float* att2 = (const float*)d_in[8];
    const float* b2   = (const float*)d_in[9];

    int E = in_sizes[1] / 2;
    const int* src = ei;
    const int* dst = ei + E;

    int gM = (N_NODES + 31) / 32;
    int gE = (E + 255) / 256;
    int gW = (N_NODES * 64 + 255) / 256;          // one wave per dst node

    wconv_all<<<(F_IN * F_H + 255) / 256, 256, 0, stream>>>(Wl1, Wr1, Wl2, Wr2);

    // CSR by dst (no feature atomics anywhere downstream)
    csr_zero<<<(N_NODES + 255) / 256, 256, 0, stream>>>();
    csr_hist<<<gE, 256, 0, stream>>>(dst, E);
    csr_scan<<<1, 1024, 0, stream>>>(E);
    csr_scatter<<<gE, 256, 0, stream>>>(src, dst, E);

    // ---- layer 1 ----
    gemm1<<<gM, 256, 0, stream>>>(x);
    fuse1<<<gW, 256, 0, stream>>>(att1, b1);

    // ---- layer 2 ----
    gemm2<<<gM, 128, 0, stream>>>();
    fuse2<<<gW, 256, 0, stream>>>(att2, b2, (float*)d_out);
}